// Round 7
// baseline (789.834 us; speedup 1.0000x reference)
//
#include <hip/hip_runtime.h>

#define N_NODESC 100000
#define N_EDGESC 1600000
#define DIM 128
#define SCAN_NB 49    // ceil(100000 / 2048)
#define GB 1563       // ceil(100000 / 64) gemm blocks
#define HB 6250       // hist / scatter blocks
#define TPAD 136      // LDS tile row stride in shorts

typedef __bf16 bf16x8 __attribute__((ext_vector_type(8)));
typedef unsigned short u16x8 __attribute__((ext_vector_type(8)));
typedef float f32x4 __attribute__((ext_vector_type(4)));

__device__ __forceinline__ float asf(unsigned u) { return __uint_as_float(u); }
__device__ __forceinline__ unsigned short f2bf(float f) {
    unsigned u = __float_as_uint(f);
    u += 0x7fffu + ((u >> 16) & 1u);
    return (unsigned short)(u >> 16);
}
__device__ __forceinline__ bf16x8 pack8(const float* f) {
    u16x8 u;
    #pragma unroll
    for (int i = 0; i < 8; ++i) u[i] = f2bf(f[i]);
    return __builtin_bit_cast(bf16x8, u);
}

// ---------------- weight convert: 7 matrices fp32 [k][c] -> bf16 transposed [c][k]
__global__ __launch_bounds__(256) void k_wcvt(const float* __restrict__ w0, const float* __restrict__ w1,
                                              const float* __restrict__ w2, const float* __restrict__ w3,
                                              const float* __restrict__ w4, const float* __restrict__ w5,
                                              const float* __restrict__ w6, unsigned short* __restrict__ wt) {
    int gid = blockIdx.x * 256 + threadIdx.x;   // 0..114687
    int m = gid >> 14;
    int r = gid & 16383;
    int c = r >> 7;
    int k = r & 127;
    const float* src;
    switch (m) {
        case 0: src = w0; break; case 1: src = w1; break; case 2: src = w2; break;
        case 3: src = w3; break; case 4: src = w4; break; case 5: src = w5; break;
        default: src = w6; break;
    }
    wt[gid] = f2bf(src[k * 128 + c]);
}

// ---------------- CSR pass A: histogram + per-edge rank (8 VGPR, max occupancy)
__global__ __launch_bounds__(256) void k_hist(const int* __restrict__ ei, int* __restrict__ counts,
                                              int* __restrict__ rank) {
    int e = blockIdx.x * 256 + threadIdx.x;
    if (e < N_EDGESC) rank[e] = atomicAdd(&counts[ei[N_EDGESC + e]], 1);
}

// ---------------- CSR scan (3 phases)
__global__ __launch_bounds__(256) void k_scan_bsum(const int* __restrict__ counts, int* __restrict__ bsum) {
    __shared__ int wsh[4];
    int b = blockIdx.x, t = threadIdx.x;
    int i0 = b * 2048 + t * 8;
    int s = 0;
    #pragma unroll
    for (int k = 0; k < 8; ++k) { int i = i0 + k; s += (i < N_NODESC) ? counts[i] : 0; }
    #pragma unroll
    for (int d = 1; d < 64; d <<= 1) s += __shfl_xor(s, d, 64);
    if ((t & 63) == 0) wsh[t >> 6] = s;
    __syncthreads();
    if (t == 0) bsum[b] = wsh[0] + wsh[1] + wsh[2] + wsh[3];
}

__global__ __launch_bounds__(64) void k_scan_boff(const int* __restrict__ bsum, int* __restrict__ boff,
                                                  int* __restrict__ offs) {
    int i = threadIdx.x;
    int v = (i < SCAN_NB) ? bsum[i] : 0;
    int incl = v;
    #pragma unroll
    for (int d = 1; d < 64; d <<= 1) { int t = __shfl_up(incl, d, 64); if (i >= d) incl += t; }
    if (i < SCAN_NB) boff[i] = incl - v;
    if (i == SCAN_NB - 1) offs[N_NODESC] = incl;
}

__global__ __launch_bounds__(256) void k_scan_write(const int* __restrict__ counts, const int* __restrict__ boff,
                                                    int* __restrict__ offs) {
    __shared__ int woff[4];
    int b = blockIdx.x, t = threadIdx.x;
    int lane = t & 63, wid = t >> 6;
    int i0 = b * 2048 + t * 8;
    int c[8];
    int tsum = 0;
    #pragma unroll
    for (int k = 0; k < 8; ++k) { int i = i0 + k; c[k] = (i < N_NODESC) ? counts[i] : 0; tsum += c[k]; }
    int incl = tsum;
    #pragma unroll
    for (int d = 1; d < 64; d <<= 1) { int tt = __shfl_up(incl, d, 64); if (lane >= d) incl += tt; }
    if (lane == 63) woff[wid] = incl;
    __syncthreads();
    if (t == 0) {
        int s = 0;
        for (int k = 0; k < 4; ++k) { int tt = woff[k]; woff[k] = s; s += tt; }
    }
    __syncthreads();
    int base = boff[b] + woff[wid] + (incl - tsum);
    #pragma unroll
    for (int k = 0; k < 8; ++k) {
        int i = i0 + k;
        if (i < N_NODESC) offs[i] = base;
        base += c[k];
    }
}

// ---------------- atomic-free scatter of combined 8B edge records
__global__ __launch_bounds__(256) void k_scatter(const int* __restrict__ ei, const float* __restrict__ ew,
                                                 const int* __restrict__ offs, const int* __restrict__ rank,
                                                 int2* __restrict__ edges) {
    int e = blockIdx.x * 256 + threadIdx.x;
    if (e >= N_EDGESC) return;
    int dst = ei[N_EDGESC + e];
    int p = offs[dst] + rank[e];
    edges[p] = make_int2(ei[e], __float_as_int(ew[e]));
}

// ---------------- aggregation: one wave per node; 16 lanes per row, dwordx4 gathers,
// 16 edges in flight per loop body (4 record loads + 4 gathers per subgroup).
__global__ __launch_bounds__(256) void k_agg(const unsigned short* __restrict__ hbf, const int* __restrict__ offs,
                                             const int2* __restrict__ edges, unsigned short* __restrict__ xnbf) {
    int wid = threadIdx.x >> 6;
    int lane = threadIdx.x & 63;
    int g = lane >> 4;          // edge subgroup 0..3
    int q = lane & 15;          // feature sixteenth
    int n = blockIdx.x * 4 + wid;
    int s = offs[n], e = offs[n + 1];
    float acc[8] = {};
    float wsum = 0.f;
    for (int j = s; j < e; j += 16) {
        int idx[4];
        bool pr[4];
        int2 rec[4];
        #pragma unroll
        for (int u = 0; u < 4; ++u) {
            idx[u] = j + u * 4 + g;
            pr[u] = idx[u] < e;
            rec[u] = edges[pr[u] ? idx[u] : s];
        }
        uint4 v[4];
        float w[4];
        #pragma unroll
        for (int u = 0; u < 4; ++u) {
            w[u] = pr[u] ? __int_as_float(rec[u].y) : 0.f;
            v[u] = *(const uint4*)(hbf + (size_t)rec[u].x * 128 + q * 8);
        }
        #pragma unroll
        for (int u = 0; u < 4; ++u) {
            unsigned uu[4] = {v[u].x, v[u].y, v[u].z, v[u].w};
            #pragma unroll
            for (int k = 0; k < 4; ++k) {
                acc[2 * k]     += w[u] * asf(uu[k] << 16);
                acc[2 * k + 1] += w[u] * asf(uu[k] & 0xffff0000u);
            }
            wsum += w[u];
        }
    }
    #pragma unroll
    for (int k = 0; k < 8; ++k) {
        acc[k] += __shfl_xor(acc[k], 16, 64);
        acc[k] += __shfl_xor(acc[k], 32, 64);
    }
    wsum += __shfl_xor(wsum, 16, 64);
    wsum += __shfl_xor(wsum, 32, 64);
    float inv = 1.f / fmaxf(wsum, 1.f);
    if (lane < 16) {
        unsigned o[4];
        #pragma unroll
        for (int k = 0; k < 4; ++k)
            o[k] = (unsigned)f2bf(acc[2 * k] * inv) | ((unsigned)f2bf(acc[2 * k + 1] * inv) << 16);
        *(uint4*)(xnbf + (size_t)n * 128 + q * 8) = make_uint4(o[0], o[1], o[2], o[3]);
    }
}

// ---------------- input GEMM: hbf = bf16(relu(x @ W_in + b)); A-loads hoisted for MLP
__global__ __launch_bounds__(256, 4) void k_gemm_in(const float* __restrict__ X,
                                                    const unsigned short* __restrict__ WT,
                                                    const float* __restrict__ bias,
                                                    unsigned short* __restrict__ Hbf, int M) {
    __shared__ unsigned short tile[64 * TPAD];
    int tid = threadIdx.x;
    int lane = tid & 63;
    int wid = tid >> 6;
    int l15 = lane & 15;
    int quad = lane >> 4;
    int rowbase = blockIdx.x * 64 + wid * 16;
    int ra = min(rowbase + l15, M - 1);
    // hoist all A loads (8 x float4 in flight)
    float buf[4][8];
    #pragma unroll
    for (int kt = 0; kt < 4; ++kt) {
        int k0 = kt * 32 + quad * 8;
        *(float4*)(buf[kt])     = *(const float4*)(X + (size_t)ra * 128 + k0);
        *(float4*)(buf[kt] + 4) = *(const float4*)(X + (size_t)ra * 128 + k0 + 4);
    }
    bf16x8 a[4];
    #pragma unroll
    for (int kt = 0; kt < 4; ++kt) a[kt] = pack8(buf[kt]);
    f32x4 acc[8] = {};
    #pragma unroll
    for (int kt = 0; kt < 4; ++kt) {
        int k0 = kt * 32 + quad * 8;
        #pragma unroll
        for (int nt = 0; nt < 8; ++nt) {
            bf16x8 b = *(const bf16x8*)(WT + (nt * 16 + l15) * 128 + k0);
            acc[nt] = __builtin_amdgcn_mfma_f32_16x16x32_bf16(a[kt], b, acc[nt], 0, 0, 0);
        }
    }
    #pragma unroll
    for (int nt = 0; nt < 8; ++nt) {
        int c = nt * 16 + l15;
        float bv = bias[c];
        #pragma unroll
        for (int i = 0; i < 4; ++i) {
            int rl = wid * 16 + quad * 4 + i;
            float v = fmaxf(acc[nt][i] + bv, 0.f);
            tile[rl * TPAD + c] = f2bf(v);
        }
    }
    __syncthreads();
    int rl = tid >> 2;
    int cs = (tid & 3) * 32;
    int gr = blockIdx.x * 64 + rl;
    if (gr < M) {
        #pragma unroll
        for (int k = 0; k < 4; ++k) {
            uint4 v = *(const uint4*)(tile + rl * TPAD + cs + k * 8);
            *(uint4*)(Hbf + (size_t)gr * 128 + cs + k * 8) = v;
        }
    }
}

// ---------------- layer GEMM: t_bf16 = h@Ws + xn@Wn + (bs+bn), + column stats
// 64 rows/block, 16 rows/wave; all A-fragments hoisted (8 x 16B loads in flight).
__global__ __launch_bounds__(256, 4) void k_gemm_layer(const unsigned short* __restrict__ Abf,
                                                       const unsigned short* __restrict__ Xbf,
                                                       const unsigned short* __restrict__ WsT,
                                                       const unsigned short* __restrict__ WnT,
                                                       const float* __restrict__ bs, const float* __restrict__ bn,
                                                       unsigned short* __restrict__ Tb,
                                                       float* __restrict__ colsum, float* __restrict__ colsq,
                                                       int M) {
    __shared__ float s_sum[128];
    __shared__ float s_sq[128];
    __shared__ unsigned short tile[64 * TPAD];
    int tid = threadIdx.x;
    if (tid < 128) { s_sum[tid] = 0.f; s_sq[tid] = 0.f; }
    __syncthreads();
    int lane = tid & 63;
    int wid = tid >> 6;
    int l15 = lane & 15;
    int quad = lane >> 4;
    int rowbase = blockIdx.x * 64 + wid * 16;
    int ra = min(rowbase + l15, M - 1);
    bf16x8 ah[4], ax[4];
    #pragma unroll
    for (int kt = 0; kt < 4; ++kt) {
        int k0 = kt * 32 + quad * 8;
        ah[kt] = *(const bf16x8*)(Abf + (size_t)ra * 128 + k0);
        ax[kt] = *(const bf16x8*)(Xbf + (size_t)ra * 128 + k0);
    }
    f32x4 acc[8] = {};
    #pragma unroll
    for (int kt = 0; kt < 4; ++kt) {
        int k0 = kt * 32 + quad * 8;
        #pragma unroll
        for (int nt = 0; nt < 8; ++nt) {
            int c = nt * 16 + l15;
            bf16x8 bsv = *(const bf16x8*)(WsT + c * 128 + k0);
            bf16x8 bnv = *(const bf16x8*)(WnT + c * 128 + k0);
            acc[nt] = __builtin_amdgcn_mfma_f32_16x16x32_bf16(ah[kt], bsv, acc[nt], 0, 0, 0);
            acc[nt] = __builtin_amdgcn_mfma_f32_16x16x32_bf16(ax[kt], bnv, acc[nt], 0, 0, 0);
        }
    }
    #pragma unroll
    for (int nt = 0; nt < 8; ++nt) {
        int c = nt * 16 + l15;
        float bv = bs[c] + bn[c];
        float ps = 0.f, pq = 0.f;
        #pragma unroll
        for (int i = 0; i < 4; ++i) {
            int rl = wid * 16 + quad * 4 + i;           // local row 0..63
            int r = blockIdx.x * 64 + rl;
            float v = acc[nt][i] + bv;
            if (r < M) {
                unsigned short qv = f2bf(v);
                tile[rl * TPAD + c] = qv;
                float vq = asf((unsigned)qv << 16);
                ps += vq; pq += vq * vq;
            }
        }
        ps += __shfl_xor(ps, 16); pq += __shfl_xor(pq, 16);
        ps += __shfl_xor(ps, 32); pq += __shfl_xor(pq, 32);
        if (quad == 0) { atomicAdd(&s_sum[c], ps); atomicAdd(&s_sq[c], pq); }
    }
    __syncthreads();
    int rl = tid >> 2;
    int cs = (tid & 3) * 32;
    int gr = blockIdx.x * 64 + rl;
    if (gr < M) {
        #pragma unroll
        for (int k = 0; k < 4; ++k) {
            uint4 v = *(const uint4*)(tile + rl * TPAD + cs + k * 8);
            *(uint4*)(Tb + (size_t)gr * 128 + cs + k * 8) = v;
        }
    }
    if (tid < 128) atomicAdd(&colsum[tid], s_sum[tid]);
    else atomicAdd(&colsq[tid - 128], s_sq[tid - 128]);
}

// ---------------- BN apply + residual; residual chain lives in bf16 (Hbf)
// FINAL=0: write Hbf (bf16).  FINAL=1: write fp32 Out.
template <int RELU, int FINAL>
__global__ __launch_bounds__(256) void k_bn(const unsigned short* __restrict__ Tb,
                                            const float* __restrict__ colsum,
                                            const float* __restrict__ colsq, const float* __restrict__ gma,
                                            const float* __restrict__ bta,
                                            unsigned short* __restrict__ Hbf, float* __restrict__ Out) {
    size_t base = ((size_t)blockIdx.x * 256 + threadIdx.x) * 8;
    int c0 = (int)(base & 127);
    uint4 tv = *(const uint4*)(Tb + base);
    unsigned w[4] = {tv.x, tv.y, tv.z, tv.w};
    float tt[8];
    #pragma unroll
    for (int k = 0; k < 4; ++k) {
        tt[2 * k]     = asf(w[k] << 16);
        tt[2 * k + 1] = asf(w[k] & 0xffff0000u);
    }
    uint4 hv = *(const uint4*)(Hbf + base);
    unsigned hw[4] = {hv.x, hv.y, hv.z, hv.w};
    float hh[8];
    #pragma unroll
    for (int k = 0; k < 4; ++k) {
        hh[2 * k]     = asf(hw[k] << 16);
        hh[2 * k + 1] = asf(hw[k] & 0xffff0000u);
    }
    float ss[8], qq[8], gg[8], bb[8];
    *(float4*)ss       = *(const float4*)(colsum + c0);
    *(float4*)(ss + 4) = *(const float4*)(colsum + c0 + 4);
    *(float4*)qq       = *(const float4*)(colsq + c0);
    *(float4*)(qq + 4) = *(const float4*)(colsq + c0 + 4);
    *(float4*)gg       = *(const float4*)(gma + c0);
    *(float4*)(gg + 4) = *(const float4*)(gma + c0 + 4);
    *(float4*)bb       = *(const float4*)(bta + c0);
    *(float4*)(bb + 4) = *(const float4*)(bta + c0 + 4);
    const float invM = 1.0f / (float)N_NODESC;
    float r[8];
    #pragma unroll
    for (int j = 0; j < 8; ++j) {
        float mu = ss[j] * invM;
        float var = qq[j] * invM - mu * mu;
        float is = rsqrtf(var + 1e-5f);
        float v = (tt[j] - mu) * is * gg[j] + bb[j];
        if (RELU) v = fmaxf(v, 0.f);
        r[j] = hh[j] + v;
    }
    if (FINAL) {
        *(float4*)(Out + base)     = make_float4(r[0], r[1], r[2], r[3]);
        *(float4*)(Out + base + 4) = make_float4(r[4], r[5], r[6], r[7]);
    } else {
        unsigned o[4];
        #pragma unroll
        for (int k = 0; k < 4; ++k)
            o[k] = (unsigned)f2bf(r[2 * k]) | ((unsigned)f2bf(r[2 * k + 1]) << 16);
        *(uint4*)(Hbf + base) = make_uint4(o[0], o[1], o[2], o[3]);
    }
}

// ---------------- host
static inline size_t al256(size_t x) { return (x + 255) & ~(size_t)255; }

extern "C" void kernel_launch(void* const* d_in, const int* in_sizes, int n_in,
                              void* d_out, int out_size, void* d_ws, size_t ws_size,
                              hipStream_t stream) {
    const float* x    = (const float*)d_in[0];
    const int*   ei   = (const int*)d_in[1];
    const float* ew   = (const float*)d_in[2];
    const float* W_in = (const float*)d_in[3];
    const float* b_in = (const float*)d_in[4];
    const float* Ws[3] = {(const float*)d_in[5],  (const float*)d_in[11], (const float*)d_in[17]};
    const float* bs[3] = {(const float*)d_in[6],  (const float*)d_in[12], (const float*)d_in[18]};
    const float* Wn[3] = {(const float*)d_in[7],  (const float*)d_in[13], (const float*)d_in[19]};
    const float* bn[3] = {(const float*)d_in[8],  (const float*)d_in[14], (const float*)d_in[20]};
    const float* g[3]  = {(const float*)d_in[9],  (const float*)d_in[15], (const float*)d_in[21]};
    const float* be[3] = {(const float*)d_in[10], (const float*)d_in[16], (const float*)d_in[22]};

    char* ws = (char*)d_ws;
    size_t off = 0;
    const size_t nElem = (size_t)N_NODESC * DIM;          // 12.8M
    unsigned short* hbf    = (unsigned short*)(ws + off); off = al256(off + nElem * 2);
    unsigned short* xnbf   = (unsigned short*)(ws + off); off = al256(off + nElem * 2);
    unsigned short* tbuf   = (unsigned short*)(ws + off); off = al256(off + nElem * 2);
    unsigned short* wt     = (unsigned short*)(ws + off); off = al256(off + 7 * 16384 * 2);
    int*            counts = (int*)(ws + off);            off = al256(off + (size_t)N_NODESC * 4);
    int*            offs   = (int*)(ws + off);            off = al256(off + ((size_t)N_NODESC + 1) * 4);
    int*            rank   = (int*)(ws + off);            off = al256(off + (size_t)N_EDGESC * 4);
    int2*           edges  = (int2*)(ws + off);           off = al256(off + (size_t)N_EDGESC * 8);
    int*            bsum_  = (int*)(ws + off);            off = al256(off + SCAN_NB * 4);
    int*            boff_  = (int*)(ws + off);            off = al256(off + SCAN_NB * 4);
    float*          stats  = (float*)(ws + off);          off = al256(off + 3 * 256 * 4);

    (void)hipMemsetAsync(counts, 0, (size_t)N_NODESC * 4, stream);
    (void)hipMemsetAsync(stats, 0, 3 * 256 * 4, stream);

    k_wcvt<<<448, 256, 0, stream>>>(W_in, Ws[0], Wn[0], Ws[1], Wn[1], Ws[2], Wn[2], wt);
    k_hist<<<HB, 256, 0, stream>>>(ei, counts, rank);
    k_scan_bsum<<<SCAN_NB, 256, 0, stream>>>(counts, bsum_);
    k_scan_boff<<<1, 64, 0, stream>>>(bsum_, boff_, offs);
    k_scan_write<<<SCAN_NB, 256, 0, stream>>>(counts, boff_, offs);
    k_scatter<<<HB, 256, 0, stream>>>(ei, ew, offs, rank, edges);

    k_gemm_in<<<GB, 256, 0, stream>>>(x, wt, b_in, hbf, N_NODESC);

    for (int l = 0; l < 3; ++l) {
        k_agg<<<25000, 256, 0, stream>>>(hbf, offs, edges, xnbf);
        k_gemm_layer<<<GB, 256, 0, stream>>>(hbf, xnbf,
                                             wt + (size_t)(1 + 2 * l) * 16384,
                                             wt + (size_t)(2 + 2 * l) * 16384,
                                             bs[l], bn[l], tbuf,
                                             stats + l * 256, stats + l * 256 + 128, N_NODESC);
        if (l < 2)
            k_bn<1, 0><<<HB, 256, 0, stream>>>(tbuf, stats + l * 256, stats + l * 256 + 128,
                                               g[l], be[l], hbf, nullptr);
        else
            k_bn<0, 1><<<HB, 256, 0, stream>>>(tbuf, stats + l * 256, stats + l * 256 + 128,
                                               g[l], be[l], hbf, (float*)d_out);
    }
}

// Round 8
// 645.389 us; speedup vs baseline: 1.2238x; 1.2238x over previous
//
#include <hip/hip_runtime.h>

#define N_NODESC 100000
#define N_EDGESC 1600000
#define DIM 128
#define SCAN_NB 49    // ceil(100000 / 2048)
#define GB 782        // ceil(100000 / 128) gemm blocks
#define HB 6250       // hist / scatter blocks
#define TPAD 136      // LDS tile row stride in shorts

typedef __bf16 bf16x8 __attribute__((ext_vector_type(8)));
typedef unsigned short u16x8 __attribute__((ext_vector_type(8)));
typedef float f32x4 __attribute__((ext_vector_type(4)));

__device__ __forceinline__ float asf(unsigned u) { return __uint_as_float(u); }
__device__ __forceinline__ unsigned short f2bf(float f) {
    unsigned u = __float_as_uint(f);
    u += 0x7fffu + ((u >> 16) & 1u);
    return (unsigned short)(u >> 16);
}
__device__ __forceinline__ bf16x8 pack8(const float* f) {
    u16x8 u;
    #pragma unroll
    for (int i = 0; i < 8; ++i) u[i] = f2bf(f[i]);
    return __builtin_bit_cast(bf16x8, u);
}

// ---------------- weight convert: 7 matrices fp32 [k][c] -> bf16 FRAGMENT-MAJOR:
// linear index = ((kt*8 + nt)*64 + lane)*8 + j  maps to  W[(kt*32 + quad*8 + j)*128 + nt*16 + l15]
// so each MFMA B-fragment load is wave-uniform base + lane*16B (one coalesced 1KB burst).
__global__ __launch_bounds__(256) void k_wcvt(const float* __restrict__ w0, const float* __restrict__ w1,
                                              const float* __restrict__ w2, const float* __restrict__ w3,
                                              const float* __restrict__ w4, const float* __restrict__ w5,
                                              const float* __restrict__ w6, unsigned short* __restrict__ wt) {
    int gid = blockIdx.x * 256 + threadIdx.x;   // 0..114687
    int m = gid >> 14;
    int r = gid & 16383;
    int j = r & 7;
    int lane = (r >> 3) & 63;
    int nt = (r >> 9) & 7;
    int kt = (r >> 12) & 3;
    int quad = lane >> 4;
    int l15 = lane & 15;
    const float* src;
    switch (m) {
        case 0: src = w0; break; case 1: src = w1; break; case 2: src = w2; break;
        case 3: src = w3; break; case 4: src = w4; break; case 5: src = w5; break;
        default: src = w6; break;
    }
    wt[gid] = f2bf(src[(kt * 32 + quad * 8 + j) * 128 + nt * 16 + l15]);
}

// ---------------- CSR pass A: histogram + per-edge rank (8 VGPR, max occupancy)
__global__ __launch_bounds__(256) void k_hist(const int* __restrict__ ei, int* __restrict__ counts,
                                              int* __restrict__ rank) {
    int e = blockIdx.x * 256 + threadIdx.x;
    if (e < N_EDGESC) rank[e] = atomicAdd(&counts[ei[N_EDGESC + e]], 1);
}

// ---------------- CSR scan (3 phases)
__global__ __launch_bounds__(256) void k_scan_bsum(const int* __restrict__ counts, int* __restrict__ bsum) {
    __shared__ int wsh[4];
    int b = blockIdx.x, t = threadIdx.x;
    int i0 = b * 2048 + t * 8;
    int s = 0;
    #pragma unroll
    for (int k = 0; k < 8; ++k) { int i = i0 + k; s += (i < N_NODESC) ? counts[i] : 0; }
    #pragma unroll
    for (int d = 1; d < 64; d <<= 1) s += __shfl_xor(s, d, 64);
    if ((t & 63) == 0) wsh[t >> 6] = s;
    __syncthreads();
    if (t == 0) bsum[b] = wsh[0] + wsh[1] + wsh[2] + wsh[3];
}

__global__ __launch_bounds__(64) void k_scan_boff(const int* __restrict__ bsum, int* __restrict__ boff,
                                                  int* __restrict__ offs) {
    int i = threadIdx.x;
    int v = (i < SCAN_NB) ? bsum[i] : 0;
    int incl = v;
    #pragma unroll
    for (int d = 1; d < 64; d <<= 1) { int t = __shfl_up(incl, d, 64); if (i >= d) incl += t; }
    if (i < SCAN_NB) boff[i] = incl - v;
    if (i == SCAN_NB - 1) offs[N_NODESC] = incl;
}

__global__ __launch_bounds__(256) void k_scan_write(const int* __restrict__ counts, const int* __restrict__ boff,
                                                    int* __restrict__ offs) {
    __shared__ int woff[4];
    int b = blockIdx.x, t = threadIdx.x;
    int lane = t & 63, wid = t >> 6;
    int i0 = b * 2048 + t * 8;
    int c[8];
    int tsum = 0;
    #pragma unroll
    for (int k = 0; k < 8; ++k) { int i = i0 + k; c[k] = (i < N_NODESC) ? counts[i] : 0; tsum += c[k]; }
    int incl = tsum;
    #pragma unroll
    for (int d = 1; d < 64; d <<= 1) { int tt = __shfl_up(incl, d, 64); if (lane >= d) incl += tt; }
    if (lane == 63) woff[wid] = incl;
    __syncthreads();
    if (t == 0) {
        int s = 0;
        for (int k = 0; k < 4; ++k) { int tt = woff[k]; woff[k] = s; s += tt; }
    }
    __syncthreads();
    int base = boff[b] + woff[wid] + (incl - tsum);
    #pragma unroll
    for (int k = 0; k < 8; ++k) {
        int i = i0 + k;
        if (i < N_NODESC) offs[i] = base;
        base += c[k];
    }
}

// ---------------- atomic-free scatter of combined 8B edge records
__global__ __launch_bounds__(256) void k_scatter(const int* __restrict__ ei, const float* __restrict__ ew,
                                                 const int* __restrict__ offs, const int* __restrict__ rank,
                                                 int2* __restrict__ edges) {
    int e = blockIdx.x * 256 + threadIdx.x;
    if (e >= N_EDGESC) return;
    int dst = ei[N_EDGESC + e];
    int p = offs[dst] + rank[e];
    edges[p] = make_int2(ei[e], __float_as_int(ew[e]));
}

// ---------------- aggregation: one wave per node; 16 lanes per row, dwordx4 gathers,
// 16 edges in flight per loop body.
__global__ __launch_bounds__(256) void k_agg(const unsigned short* __restrict__ hbf, const int* __restrict__ offs,
                                             const int2* __restrict__ edges, unsigned short* __restrict__ xnbf) {
    int wid = threadIdx.x >> 6;
    int lane = threadIdx.x & 63;
    int g = lane >> 4;          // edge subgroup 0..3
    int q = lane & 15;          // feature sixteenth
    int n = blockIdx.x * 4 + wid;
    int s = offs[n], e = offs[n + 1];
    float acc[8] = {};
    float wsum = 0.f;
    for (int j = s; j < e; j += 16) {
        int idx[4];
        bool pr[4];
        int2 rec[4];
        #pragma unroll
        for (int u = 0; u < 4; ++u) {
            idx[u] = j + u * 4 + g;
            pr[u] = idx[u] < e;
            rec[u] = edges[pr[u] ? idx[u] : s];
        }
        uint4 v[4];
        float w[4];
        #pragma unroll
        for (int u = 0; u < 4; ++u) {
            w[u] = pr[u] ? __int_as_float(rec[u].y) : 0.f;
            v[u] = *(const uint4*)(hbf + (size_t)rec[u].x * 128 + q * 8);
        }
        #pragma unroll
        for (int u = 0; u < 4; ++u) {
            unsigned uu[4] = {v[u].x, v[u].y, v[u].z, v[u].w};
            #pragma unroll
            for (int k = 0; k < 4; ++k) {
                acc[2 * k]     += w[u] * asf(uu[k] << 16);
                acc[2 * k + 1] += w[u] * asf(uu[k] & 0xffff0000u);
            }
            wsum += w[u];
        }
    }
    #pragma unroll
    for (int k = 0; k < 8; ++k) {
        acc[k] += __shfl_xor(acc[k], 16, 64);
        acc[k] += __shfl_xor(acc[k], 32, 64);
    }
    wsum += __shfl_xor(wsum, 16, 64);
    wsum += __shfl_xor(wsum, 32, 64);
    float inv = 1.f / fmaxf(wsum, 1.f);
    if (lane < 16) {
        unsigned o[4];
        #pragma unroll
        for (int k = 0; k < 4; ++k)
            o[k] = (unsigned)f2bf(acc[2 * k] * inv) | ((unsigned)f2bf(acc[2 * k + 1] * inv) << 16);
        *(uint4*)(xnbf + (size_t)n * 128 + q * 8) = make_uint4(o[0], o[1], o[2], o[3]);
    }
}

// ---------------- input GEMM: hbf = bf16(relu(x @ W_in + b)); 128 rows/block,
// 2 row-fragments/wave, fragment-major coalesced weights, LDS-staged store.
__global__ __launch_bounds__(256, 2) void k_gemm_in(const float* __restrict__ X,
                                                    const unsigned short* __restrict__ WF,
                                                    const float* __restrict__ bias,
                                                    unsigned short* __restrict__ Hbf, int M) {
    __shared__ unsigned short tile[128 * TPAD];
    int tid = threadIdx.x;
    int lane = tid & 63;
    int wid = tid >> 6;
    int l15 = lane & 15;
    int quad = lane >> 4;
    int rowbase = blockIdx.x * 128 + wid * 32;
    bf16x8 a[2][4];
    #pragma unroll
    for (int rs = 0; rs < 2; ++rs) {
        int ra = min(rowbase + rs * 16 + l15, M - 1);
        float buf[4][8];
        #pragma unroll
        for (int kt = 0; kt < 4; ++kt) {
            int k0 = kt * 32 + quad * 8;
            *(float4*)(buf[kt])     = *(const float4*)(X + (size_t)ra * 128 + k0);
            *(float4*)(buf[kt] + 4) = *(const float4*)(X + (size_t)ra * 128 + k0 + 4);
        }
        #pragma unroll
        for (int kt = 0; kt < 4; ++kt) a[rs][kt] = pack8(buf[kt]);
    }
    f32x4 acc[2][8] = {};
    #pragma unroll
    for (int kt = 0; kt < 4; ++kt) {
        #pragma unroll
        for (int nt = 0; nt < 8; ++nt) {
            bf16x8 b = *(const bf16x8*)(WF + ((kt * 8 + nt) * 64 + lane) * 8);
            #pragma unroll
            for (int rs = 0; rs < 2; ++rs)
                acc[rs][nt] = __builtin_amdgcn_mfma_f32_16x16x32_bf16(a[rs][kt], b, acc[rs][nt], 0, 0, 0);
        }
    }
    #pragma unroll
    for (int nt = 0; nt < 8; ++nt) {
        int c = nt * 16 + l15;
        float bv = bias[c];
        #pragma unroll
        for (int rs = 0; rs < 2; ++rs) {
            #pragma unroll
            for (int i = 0; i < 4; ++i) {
                int rl = wid * 32 + rs * 16 + quad * 4 + i;
                float v = fmaxf(acc[rs][nt][i] + bv, 0.f);
                tile[rl * TPAD + c] = f2bf(v);
            }
        }
    }
    __syncthreads();
    int rl = tid >> 1;
    int cs = (tid & 1) * 64;
    int gr = blockIdx.x * 128 + rl;
    if (gr < M) {
        #pragma unroll
        for (int k = 0; k < 8; ++k) {
            uint4 v = *(const uint4*)(tile + rl * TPAD + cs + k * 8);
            *(uint4*)(Hbf + (size_t)gr * 128 + cs + k * 8) = v;
        }
    }
}

// ---------------- layer GEMM: t_bf16 = h@Ws + xn@Wn + (bs+bn), + column stats
// 128 rows/block, 2 row-fragments/wave, fragment-major weights, LDS-staged store.
__global__ __launch_bounds__(256, 2) void k_gemm_layer(const unsigned short* __restrict__ Abf,
                                                       const unsigned short* __restrict__ Xbf,
                                                       const unsigned short* __restrict__ WsF,
                                                       const unsigned short* __restrict__ WnF,
                                                       const float* __restrict__ bs, const float* __restrict__ bn,
                                                       unsigned short* __restrict__ Tb,
                                                       float* __restrict__ colsum, float* __restrict__ colsq,
                                                       int M) {
    __shared__ float s_sum[128];
    __shared__ float s_sq[128];
    __shared__ unsigned short tile[128 * TPAD];
    int tid = threadIdx.x;
    if (tid < 128) { s_sum[tid] = 0.f; s_sq[tid] = 0.f; }
    __syncthreads();
    int lane = tid & 63;
    int wid = tid >> 6;
    int l15 = lane & 15;
    int quad = lane >> 4;
    int rowbase = blockIdx.x * 128 + wid * 32;
    bf16x8 ah[2][4], ax[2][4];
    #pragma unroll
    for (int rs = 0; rs < 2; ++rs) {
        int ra = min(rowbase + rs * 16 + l15, M - 1);
        #pragma unroll
        for (int kt = 0; kt < 4; ++kt) {
            int k0 = kt * 32 + quad * 8;
            ah[rs][kt] = *(const bf16x8*)(Abf + (size_t)ra * 128 + k0);
            ax[rs][kt] = *(const bf16x8*)(Xbf + (size_t)ra * 128 + k0);
        }
    }
    f32x4 acc[2][8] = {};
    #pragma unroll
    for (int kt = 0; kt < 4; ++kt) {
        #pragma unroll
        for (int nt = 0; nt < 8; ++nt) {
            bf16x8 bsv = *(const bf16x8*)(WsF + ((kt * 8 + nt) * 64 + lane) * 8);
            bf16x8 bnv = *(const bf16x8*)(WnF + ((kt * 8 + nt) * 64 + lane) * 8);
            #pragma unroll
            for (int rs = 0; rs < 2; ++rs) {
                acc[rs][nt] = __builtin_amdgcn_mfma_f32_16x16x32_bf16(ah[rs][kt], bsv, acc[rs][nt], 0, 0, 0);
                acc[rs][nt] = __builtin_amdgcn_mfma_f32_16x16x32_bf16(ax[rs][kt], bnv, acc[rs][nt], 0, 0, 0);
            }
        }
    }
    #pragma unroll
    for (int nt = 0; nt < 8; ++nt) {
        int c = nt * 16 + l15;
        float bv = bs[c] + bn[c];
        float ps = 0.f, pq = 0.f;
        #pragma unroll
        for (int rs = 0; rs < 2; ++rs) {
            #pragma unroll
            for (int i = 0; i < 4; ++i) {
                int rl = wid * 32 + rs * 16 + quad * 4 + i;   // local row 0..127
                int r = blockIdx.x * 128 + rl;
                float v = acc[rs][nt][i] + bv;
                if (r < M) {
                    unsigned short qv = f2bf(v);
                    tile[rl * TPAD + c] = qv;
                    float vq = asf((unsigned)qv << 16);
                    ps += vq; pq += vq * vq;
                }
            }
        }
        ps += __shfl_xor(ps, 16); pq += __shfl_xor(pq, 16);
        ps += __shfl_xor(ps, 32); pq += __shfl_xor(pq, 32);
        if (quad == 0) { atomicAdd(&s_sum[c], ps); atomicAdd(&s_sq[c], pq); }
    }
    __syncthreads();
    int rl = tid >> 1;
    int cs = (tid & 1) * 64;
    int gr = blockIdx.x * 128 + rl;
    if (gr < M) {
        #pragma unroll
        for (int k = 0; k < 8; ++k) {
            uint4 v = *(const uint4*)(tile + rl * TPAD + cs + k * 8);
            *(uint4*)(Tb + (size_t)gr * 128 + cs + k * 8) = v;
        }
    }
    if (tid < 128) atomicAdd(&colsum[tid], s_sum[tid]);
    else atomicAdd(&colsq[tid - 128], s_sq[tid - 128]);
}

// ---------------- BN apply + residual; residual chain lives in bf16 (Hbf)
// FINAL=0: write Hbf (bf16).  FINAL=1: write fp32 Out.
template <int RELU, int FINAL>
__global__ __launch_bounds__(256) void k_bn(const unsigned short* __restrict__ Tb,
                                            const float* __restrict__ colsum,
                                            const float* __restrict__ colsq, const float* __restrict__ gma,
                                            const float* __restrict__ bta,
                                            unsigned short* __restrict__ Hbf, float* __restrict__ Out) {
    size_t base = ((size_t)blockIdx.x * 256 + threadIdx.x) * 8;
    int c0 = (int)(base & 127);
    uint4 tv = *(const uint4*)(Tb + base);
    unsigned w[4] = {tv.x, tv.y, tv.z, tv.w};
    float tt[8];
    #pragma unroll
    for (int k = 0; k < 4; ++k) {
        tt[2 * k]     = asf(w[k] << 16);
        tt[2 * k + 1] = asf(w[k] & 0xffff0000u);
    }
    uint4 hv = *(const uint4*)(Hbf + base);
    unsigned hw[4] = {hv.x, hv.y, hv.z, hv.w};
    float hh[8];
    #pragma unroll
    for (int k = 0; k < 4; ++k) {
        hh[2 * k]     = asf(hw[k] << 16);
        hh[2 * k + 1] = asf(hw[k] & 0xffff0000u);
    }
    float ss[8], qq[8], gg[8], bb[8];
    *(float4*)ss       = *(const float4*)(colsum + c0);
    *(float4*)(ss + 4) = *(const float4*)(colsum + c0 + 4);
    *(float4*)qq       = *(const float4*)(colsq + c0);
    *(float4*)(qq + 4) = *(const float4*)(colsq + c0 + 4);
    *(float4*)gg       = *(const float4*)(gma + c0);
    *(float4*)(gg + 4) = *(const float4*)(gma + c0 + 4);
    *(float4*)bb       = *(const float4*)(bta + c0);
    *(float4*)(bb + 4) = *(const float4*)(bta + c0 + 4);
    const float invM = 1.0f / (float)N_NODESC;
    float r[8];
    #pragma unroll
    for (int j = 0; j < 8; ++j) {
        float mu = ss[j] * invM;
        float var = qq[j] * invM - mu * mu;
        float is = rsqrtf(var + 1e-5f);
        float v = (tt[j] - mu) * is * gg[j] + bb[j];
        if (RELU) v = fmaxf(v, 0.f);
        r[j] = hh[j] + v;
    }
    if (FINAL) {
        *(float4*)(Out + base)     = make_float4(r[0], r[1], r[2], r[3]);
        *(float4*)(Out + base + 4) = make_float4(r[4], r[5], r[6], r[7]);
    } else {
        unsigned o[4];
        #pragma unroll
        for (int k = 0; k < 4; ++k)
            o[k] = (unsigned)f2bf(r[2 * k]) | ((unsigned)f2bf(r[2 * k + 1]) << 16);
        *(uint4*)(Hbf + base) = make_uint4(o[0], o[1], o[2], o[3]);
    }
}

// ---------------- host
static inline size_t al256(size_t x) { return (x + 255) & ~(size_t)255; }

extern "C" void kernel_launch(void* const* d_in, const int* in_sizes, int n_in,
                              void* d_out, int out_size, void* d_ws, size_t ws_size,
                              hipStream_t stream) {
    const float* x    = (const float*)d_in[0];
    const int*   ei   = (const int*)d_in[1];
    const float* ew   = (const float*)d_in[2];
    const float* W_in = (const float*)d_in[3];
    const float* b_in = (const float*)d_in[4];
    const float* Ws[3] = {(const float*)d_in[5],  (const float*)d_in[11], (const float*)d_in[17]};
    const float* bs[3] = {(const float*)d_in[6],  (const float*)d_in[12], (const float*)d_in[18]};
    const float* Wn[3] = {(const float*)d_in[7],  (const float*)d_in[13], (const float*)d_in[19]};
    const float* bn[3] = {(const float*)d_in[8],  (const float*)d_in[14], (const float*)d_in[20]};
    const float* g[3]  = {(const float*)d_in[9],  (const float*)d_in[15], (const float*)d_in[21]};
    const float* be[3] = {(const float*)d_in[10], (const float*)d_in[16], (const float*)d_in[22]};

    char* ws = (char*)d_ws;
    size_t off = 0;
    const size_t nElem = (size_t)N_NODESC * DIM;          // 12.8M
    unsigned short* hbf    = (unsigned short*)(ws + off); off = al256(off + nElem * 2);
    unsigned short* xnbf   = (unsigned short*)(ws + off); off = al256(off + nElem * 2);
    unsigned short* tbuf   = (unsigned short*)(ws + off); off = al256(off + nElem * 2);
    unsigned short* wt     = (unsigned short*)(ws + off); off = al256(off + 7 * 16384 * 2);
    int*            counts = (int*)(ws + off);            off = al256(off + (size_t)N_NODESC * 4);
    int*            offs   = (int*)(ws + off);            off = al256(off + ((size_t)N_NODESC + 1) * 4);
    int*            rank   = (int*)(ws + off);            off = al256(off + (size_t)N_EDGESC * 4);
    int2*           edges  = (int2*)(ws + off);           off = al256(off + (size_t)N_EDGESC * 8);
    int*            bsum_  = (int*)(ws + off);            off = al256(off + SCAN_NB * 4);
    int*            boff_  = (int*)(ws + off);            off = al256(off + SCAN_NB * 4);
    float*          stats  = (float*)(ws + off);          off = al256(off + 3 * 256 * 4);

    (void)hipMemsetAsync(counts, 0, (size_t)N_NODESC * 4, stream);
    (void)hipMemsetAsync(stats, 0, 3 * 256 * 4, stream);

    k_wcvt<<<448, 256, 0, stream>>>(W_in, Ws[0], Wn[0], Ws[1], Wn[1], Ws[2], Wn[2], wt);
    k_hist<<<HB, 256, 0, stream>>>(ei, counts, rank);
    k_scan_bsum<<<SCAN_NB, 256, 0, stream>>>(counts, bsum_);
    k_scan_boff<<<1, 64, 0, stream>>>(bsum_, boff_, offs);
    k_scan_write<<<SCAN_NB, 256, 0, stream>>>(counts, boff_, offs);
    k_scatter<<<HB, 256, 0, stream>>>(ei, ew, offs, rank, edges);

    k_gemm_in<<<GB, 256, 0, stream>>>(x, wt, b_in, hbf, N_NODESC);

    for (int l = 0; l < 3; ++l) {
        k_agg<<<25000, 256, 0, stream>>>(hbf, offs, edges, xnbf);
        k_gemm_layer<<<GB, 256, 0, stream>>>(hbf, xnbf,
                                             wt + (size_t)(1 + 2 * l) * 16384,
                                             wt + (size_t)(2 + 2 * l) * 16384,
                                             bs[l], bn[l], tbuf,
                                             stats + l * 256, stats + l * 256 + 128, N_NODESC);
        if (l < 2)
            k_bn<1, 0><<<HB, 256, 0, stream>>>(tbuf, stats + l * 256, stats + l * 256 + 128,
                                               g[l], be[l], hbf, nullptr);
        else
            k_bn<0, 1><<<HB, 256, 0, stream>>>(tbuf, stats + l * 256, stats + l * 256 + 128,
                                               g[l], be[l], hbf, (float*)d_out);
    }
}

// Round 9
// 644.543 us; speedup vs baseline: 1.2254x; 1.0013x over previous
//
#include <hip/hip_runtime.h>

#define N_NODESC 100000
#define N_EDGESC 1600000
#define DIM 128
#define SCAN_NB 49    // ceil(100000 / 2048)
#define GB 782        // ceil(100000 / 128) gemm blocks
#define HB 6250       // hist / scatter blocks
#define TPAD 136      // LDS tile row stride in shorts

typedef __bf16 bf16x8 __attribute__((ext_vector_type(8)));
typedef unsigned short u16x8 __attribute__((ext_vector_type(8)));
typedef float f32x4 __attribute__((ext_vector_type(4)));

__device__ __forceinline__ float asf(unsigned u) { return __uint_as_float(u); }
__device__ __forceinline__ unsigned short f2bf(float f) {
    unsigned u = __float_as_uint(f);
    u += 0x7fffu + ((u >> 16) & 1u);
    return (unsigned short)(u >> 16);
}
__device__ __forceinline__ bf16x8 pack8(const float* f) {
    u16x8 u;
    #pragma unroll
    for (int i = 0; i < 8; ++i) u[i] = f2bf(f[i]);
    return __builtin_bit_cast(bf16x8, u);
}

// ---------------- weight convert: 7 matrices fp32 [k][c] -> bf16 FRAGMENT-MAJOR:
// linear index = ((kt*8 + nt)*64 + lane)*8 + j  maps to  W[(kt*32 + quad*8 + j)*128 + nt*16 + l15]
// so each MFMA B-fragment load is wave-uniform base + lane*16B (one coalesced 1KB burst).
__global__ __launch_bounds__(256) void k_wcvt(const float* __restrict__ w0, const float* __restrict__ w1,
                                              const float* __restrict__ w2, const float* __restrict__ w3,
                                              const float* __restrict__ w4, const float* __restrict__ w5,
                                              const float* __restrict__ w6, unsigned short* __restrict__ wt) {
    int gid = blockIdx.x * 256 + threadIdx.x;   // 0..114687
    int m = gid >> 14;
    int r = gid & 16383;
    int j = r & 7;
    int lane = (r >> 3) & 63;
    int nt = (r >> 9) & 7;
    int kt = (r >> 12) & 3;
    int quad = lane >> 4;
    int l15 = lane & 15;
    const float* src;
    switch (m) {
        case 0: src = w0; break; case 1: src = w1; break; case 2: src = w2; break;
        case 3: src = w3; break; case 4: src = w4; break; case 5: src = w5; break;
        default: src = w6; break;
    }
    wt[gid] = f2bf(src[(kt * 32 + quad * 8 + j) * 128 + nt * 16 + l15]);
}

// ---------------- CSR pass A: histogram + per-edge rank (low VGPR, max occupancy)
__global__ __launch_bounds__(256) void k_hist(const int* __restrict__ ei, int* __restrict__ counts,
                                              int* __restrict__ rank) {
    int e = blockIdx.x * 256 + threadIdx.x;
    if (e < N_EDGESC) rank[e] = atomicAdd(&counts[ei[N_EDGESC + e]], 1);
}

// ---------------- CSR scan phase 1: per-block (2048 counts) sums
__global__ __launch_bounds__(256) void k_scan_bsum(const int* __restrict__ counts, int* __restrict__ bsum) {
    __shared__ int wsh[4];
    int b = blockIdx.x, t = threadIdx.x;
    int i0 = b * 2048 + t * 8;
    int s = 0;
    #pragma unroll
    for (int k = 0; k < 8; ++k) { int i = i0 + k; s += (i < N_NODESC) ? counts[i] : 0; }
    #pragma unroll
    for (int d = 1; d < 64; d <<= 1) s += __shfl_xor(s, d, 64);
    if ((t & 63) == 0) wsh[t >> 6] = s;
    __syncthreads();
    if (t == 0) bsum[b] = wsh[0] + wsh[1] + wsh[2] + wsh[3];
}

// ---------------- CSR scan phase 2: write exclusive prefixes (block prefix recomputed
// in-kernel from bsum[] — SCAN_NB=49 fits one wave, saves a launch)
__global__ __launch_bounds__(256) void k_scan_write(const int* __restrict__ counts, const int* __restrict__ bsum,
                                                    int* __restrict__ offs) {
    __shared__ int woff[4];
    __shared__ int bbase_sh;
    int b = blockIdx.x, t = threadIdx.x;
    int lane = t & 63, wid = t >> 6;
    if (t < 64) {
        int vp = (t < b) ? bsum[t] : 0;                 // prefix of blocks before b
        int va = (t < SCAN_NB) ? bsum[t] : 0;           // full total
        #pragma unroll
        for (int d = 1; d < 64; d <<= 1) { vp += __shfl_xor(vp, d, 64); va += __shfl_xor(va, d, 64); }
        if (t == 0) {
            bbase_sh = vp;
            if (b == SCAN_NB - 1) offs[N_NODESC] = va;
        }
    }
    __syncthreads();
    int i0 = b * 2048 + t * 8;
    int c[8];
    int tsum = 0;
    #pragma unroll
    for (int k = 0; k < 8; ++k) { int i = i0 + k; c[k] = (i < N_NODESC) ? counts[i] : 0; tsum += c[k]; }
    int incl = tsum;
    #pragma unroll
    for (int d = 1; d < 64; d <<= 1) { int tt = __shfl_up(incl, d, 64); if (lane >= d) incl += tt; }
    if (lane == 63) woff[wid] = incl;
    __syncthreads();
    if (t == 0) {
        int s = 0;
        for (int k = 0; k < 4; ++k) { int tt = woff[k]; woff[k] = s; s += tt; }
    }
    __syncthreads();
    int base = bbase_sh + woff[wid] + (incl - tsum);
    #pragma unroll
    for (int k = 0; k < 8; ++k) {
        int i = i0 + k;
        if (i < N_NODESC) offs[i] = base;
        base += c[k];
    }
}

// ---------------- atomic-free scatter of combined 8B edge records
__global__ __launch_bounds__(256) void k_scatter(const int* __restrict__ ei, const float* __restrict__ ew,
                                                 const int* __restrict__ offs, const int* __restrict__ rank,
                                                 int2* __restrict__ edges) {
    int e = blockIdx.x * 256 + threadIdx.x;
    if (e >= N_EDGESC) return;
    int dst = ei[N_EDGESC + e];
    int p = offs[dst] + rank[e];
    edges[p] = make_int2(ei[e], __float_as_int(ew[e]));
}

// ---------------- aggregation: HALF-WAVE per node (2 nodes/wave); within a half-wave,
// 2 edge-subgroups x 16 feature-lanes, 4-deep unroll = 8 edges in flight per node.
__global__ __launch_bounds__(256) void k_agg(const unsigned short* __restrict__ hbf, const int* __restrict__ offs,
                                             const int2* __restrict__ edges, unsigned short* __restrict__ xnbf) {
    int tid = threadIdx.x;
    int q = tid & 15;                 // feature sixteenth
    int sub = (tid >> 4) & 1;         // edge subgroup within half-wave
    int n = blockIdx.x * 8 + (tid >> 5);   // 8 nodes per 256-thread block
    int s = offs[n], e = offs[n + 1];
    float acc[8] = {};
    float wsum = 0.f;
    for (int j = s; j < e; j += 8) {
        int idx[4];
        bool pr[4];
        int2 rec[4];
        #pragma unroll
        for (int u = 0; u < 4; ++u) {
            idx[u] = j + u * 2 + sub;
            pr[u] = idx[u] < e;
            rec[u] = edges[pr[u] ? idx[u] : s];
        }
        uint4 v[4];
        float w[4];
        #pragma unroll
        for (int u = 0; u < 4; ++u) {
            w[u] = pr[u] ? __int_as_float(rec[u].y) : 0.f;
            v[u] = *(const uint4*)(hbf + (size_t)rec[u].x * 128 + q * 8);
        }
        #pragma unroll
        for (int u = 0; u < 4; ++u) {
            unsigned uu[4] = {v[u].x, v[u].y, v[u].z, v[u].w};
            #pragma unroll
            for (int k = 0; k < 4; ++k) {
                acc[2 * k]     += w[u] * asf(uu[k] << 16);
                acc[2 * k + 1] += w[u] * asf(uu[k] & 0xffff0000u);
            }
            wsum += w[u];
        }
    }
    // combine the two 16-lane subgroups of each half-wave (xor 16 stays within half-wave)
    #pragma unroll
    for (int k = 0; k < 8; ++k) acc[k] += __shfl_xor(acc[k], 16, 64);
    wsum += __shfl_xor(wsum, 16, 64);
    float inv = 1.f / fmaxf(wsum, 1.f);
    if (((tid >> 4) & 1) == 0) {     // lanes 0-15 / 32-47 write their node's row
        unsigned o[4];
        #pragma unroll
        for (int k = 0; k < 4; ++k)
            o[k] = (unsigned)f2bf(acc[2 * k] * inv) | ((unsigned)f2bf(acc[2 * k + 1] * inv) << 16);
        *(uint4*)(xnbf + (size_t)n * 128 + q * 8) = make_uint4(o[0], o[1], o[2], o[3]);
    }
}

// ---------------- input GEMM: hbf = bf16(relu(x @ W_in + b)); 128 rows/block,
// 2 row-fragments/wave, fragment-major coalesced weights, LDS-staged store.
__global__ __launch_bounds__(256, 3) void k_gemm_in(const float* __restrict__ X,
                                                    const unsigned short* __restrict__ WF,
                                                    const float* __restrict__ bias,
                                                    unsigned short* __restrict__ Hbf, int M) {
    __shared__ unsigned short tile[128 * TPAD];
    int tid = threadIdx.x;
    int lane = tid & 63;
    int wid = tid >> 6;
    int l15 = lane & 15;
    int quad = lane >> 4;
    int rowbase = blockIdx.x * 128 + wid * 32;
    bf16x8 a[2][4];
    #pragma unroll
    for (int rs = 0; rs < 2; ++rs) {
        int ra = min(rowbase + rs * 16 + l15, M - 1);
        float buf[4][8];
        #pragma unroll
        for (int kt = 0; kt < 4; ++kt) {
            int k0 = kt * 32 + quad * 8;
            *(float4*)(buf[kt])     = *(const float4*)(X + (size_t)ra * 128 + k0);
            *(float4*)(buf[kt] + 4) = *(const float4*)(X + (size_t)ra * 128 + k0 + 4);
        }
        #pragma unroll
        for (int kt = 0; kt < 4; ++kt) a[rs][kt] = pack8(buf[kt]);
    }
    f32x4 acc[2][8] = {};
    #pragma unroll
    for (int kt = 0; kt < 4; ++kt) {
        #pragma unroll
        for (int nt = 0; nt < 8; ++nt) {
            bf16x8 b = *(const bf16x8*)(WF + ((kt * 8 + nt) * 64 + lane) * 8);
            #pragma unroll
            for (int rs = 0; rs < 2; ++rs)
                acc[rs][nt] = __builtin_amdgcn_mfma_f32_16x16x32_bf16(a[rs][kt], b, acc[rs][nt], 0, 0, 0);
        }
    }
    #pragma unroll
    for (int nt = 0; nt < 8; ++nt) {
        int c = nt * 16 + l15;
        float bv = bias[c];
        #pragma unroll
        for (int rs = 0; rs < 2; ++rs) {
            #pragma unroll
            for (int i = 0; i < 4; ++i) {
                int rl = wid * 32 + rs * 16 + quad * 4 + i;
                float v = fmaxf(acc[rs][nt][i] + bv, 0.f);
                tile[rl * TPAD + c] = f2bf(v);
            }
        }
    }
    __syncthreads();
    int rl = tid >> 1;
    int cs = (tid & 1) * 64;
    int gr = blockIdx.x * 128 + rl;
    if (gr < M) {
        #pragma unroll
        for (int k = 0; k < 8; ++k) {
            uint4 v = *(const uint4*)(tile + rl * TPAD + cs + k * 8);
            *(uint4*)(Hbf + (size_t)gr * 128 + cs + k * 8) = v;
        }
    }
}

// ---------------- layer GEMM: t_bf16 = h@Ws + xn@Wn + (bs+bn), + column stats
// 128 rows/block, 2 row-fragments/wave, fragment-major weights, LDS-staged store.
__global__ __launch_bounds__(256, 3) void k_gemm_layer(const unsigned short* __restrict__ Abf,
                                                       const unsigned short* __restrict__ Xbf,
                                                       const unsigned short* __restrict__ WsF,
                                                       const unsigned short* __restrict__ WnF,
                                                       const float* __restrict__ bs, const float* __restrict__ bn,
                                                       unsigned short* __restrict__ Tb,
                                                       float* __restrict__ colsum, float* __restrict__ colsq,
                                                       int M) {
    __shared__ float s_sum[128];
    __shared__ float s_sq[128];
    __shared__ unsigned short tile[128 * TPAD];
    int tid = threadIdx.x;
    if (tid < 128) { s_sum[tid] = 0.f; s_sq[tid] = 0.f; }
    __syncthreads();
    int lane = tid & 63;
    int wid = tid >> 6;
    int l15 = lane & 15;
    int quad = lane >> 4;
    int rowbase = blockIdx.x * 128 + wid * 32;
    bf16x8 ah[2][4], ax[2][4];
    #pragma unroll
    for (int rs = 0; rs < 2; ++rs) {
        int ra = min(rowbase + rs * 16 + l15, M - 1);
        #pragma unroll
        for (int kt = 0; kt < 4; ++kt) {
            int k0 = kt * 32 + quad * 8;
            ah[rs][kt] = *(const bf16x8*)(Abf + (size_t)ra * 128 + k0);
            ax[rs][kt] = *(const bf16x8*)(Xbf + (size_t)ra * 128 + k0);
        }
    }
    f32x4 acc[2][8] = {};
    #pragma unroll
    for (int kt = 0; kt < 4; ++kt) {
        #pragma unroll
        for (int nt = 0; nt < 8; ++nt) {
            bf16x8 bsv = *(const bf16x8*)(WsF + ((kt * 8 + nt) * 64 + lane) * 8);
            bf16x8 bnv = *(const bf16x8*)(WnF + ((kt * 8 + nt) * 64 + lane) * 8);
            #pragma unroll
            for (int rs = 0; rs < 2; ++rs) {
                acc[rs][nt] = __builtin_amdgcn_mfma_f32_16x16x32_bf16(ah[rs][kt], bsv, acc[rs][nt], 0, 0, 0);
                acc[rs][nt] = __builtin_amdgcn_mfma_f32_16x16x32_bf16(ax[rs][kt], bnv, acc[rs][nt], 0, 0, 0);
            }
        }
    }
    #pragma unroll
    for (int nt = 0; nt < 8; ++nt) {
        int c = nt * 16 + l15;
        float bv = bs[c] + bn[c];
        float ps = 0.f, pq = 0.f;
        #pragma unroll
        for (int rs = 0; rs < 2; ++rs) {
            #pragma unroll
            for (int i = 0; i < 4; ++i) {
                int rl = wid * 32 + rs * 16 + quad * 4 + i;   // local row 0..127
                int r = blockIdx.x * 128 + rl;
                float v = acc[rs][nt][i] + bv;
                if (r < M) {
                    unsigned short qv = f2bf(v);
                    tile[rl * TPAD + c] = qv;
                    float vq = asf((unsigned)qv << 16);
                    ps += vq; pq += vq * vq;
                }
            }
        }
        ps += __shfl_xor(ps, 16); pq += __shfl_xor(pq, 16);
        ps += __shfl_xor(ps, 32); pq += __shfl_xor(pq, 32);
        if (quad == 0) { atomicAdd(&s_sum[c], ps); atomicAdd(&s_sq[c], pq); }
    }
    __syncthreads();
    int rl = tid >> 1;
    int cs = (tid & 1) * 64;
    int gr = blockIdx.x * 128 + rl;
    if (gr < M) {
        #pragma unroll
        for (int k = 0; k < 8; ++k) {
            uint4 v = *(const uint4*)(tile + rl * TPAD + cs + k * 8);
            *(uint4*)(Tb + (size_t)gr * 128 + cs + k * 8) = v;
        }
    }
    if (tid < 128) atomicAdd(&colsum[tid], s_sum[tid]);
    else atomicAdd(&colsq[tid - 128], s_sq[tid - 128]);
}

// ---------------- BN apply + residual; residual chain lives in bf16 (Hbf)
// FINAL=0: write Hbf (bf16).  FINAL=1: write fp32 Out.
template <int RELU, int FINAL>
__global__ __launch_bounds__(256) void k_bn(const unsigned short* __restrict__ Tb,
                                            const float* __restrict__ colsum,
                                            const float* __restrict__ colsq, const float* __restrict__ gma,
                                            const float* __restrict__ bta,
                                            unsigned short* __restrict__ Hbf, float* __restrict__ Out) {
    size_t base = ((size_t)blockIdx.x * 256 + threadIdx.x) * 8;
    int c0 = (int)(base & 127);
    uint4 tv = *(const uint4*)(Tb + base);
    unsigned w[4] = {tv.x, tv.y, tv.z, tv.w};
    float tt[8];
    #pragma unroll
    for (int k = 0; k < 4; ++k) {
        tt[2 * k]     = asf(w[k] << 16);
        tt[2 * k + 1] = asf(w[k] & 0xffff0000u);
    }
    uint4 hv = *(const uint4*)(Hbf + base);
    unsigned hw[4] = {hv.x, hv.y, hv.z, hv.w};
    float hh[8];
    #pragma unroll
    for (int k = 0; k < 4; ++k) {
        hh[2 * k]     = asf(hw[k] << 16);
        hh[2 * k + 1] = asf(hw[k] & 0xffff0000u);
    }
    float ss[8], qq[8], gg[8], bb[8];
    *(float4*)ss       = *(const float4*)(colsum + c0);
    *(float4*)(ss + 4) = *(const float4*)(colsum + c0 + 4);
    *(float4*)qq       = *(const float4*)(colsq + c0);
    *(float4*)(qq + 4) = *(const float4*)(colsq + c0 + 4);
    *(float4*)gg       = *(const float4*)(gma + c0);
    *(float4*)(gg + 4) = *(const float4*)(gma + c0 + 4);
    *(float4*)bb       = *(const float4*)(bta + c0);
    *(float4*)(bb + 4) = *(const float4*)(bta + c0 + 4);
    const float invM = 1.0f / (float)N_NODESC;
    float r[8];
    #pragma unroll
    for (int j = 0; j < 8; ++j) {
        float mu = ss[j] * invM;
        float var = qq[j] * invM - mu * mu;
        float is = rsqrtf(var + 1e-5f);
        float v = (tt[j] - mu) * is * gg[j] + bb[j];
        if (RELU) v = fmaxf(v, 0.f);
        r[j] = hh[j] + v;
    }
    if (FINAL) {
        *(float4*)(Out + base)     = make_float4(r[0], r[1], r[2], r[3]);
        *(float4*)(Out + base + 4) = make_float4(r[4], r[5], r[6], r[7]);
    } else {
        unsigned o[4];
        #pragma unroll
        for (int k = 0; k < 4; ++k)
            o[k] = (unsigned)f2bf(r[2 * k]) | ((unsigned)f2bf(r[2 * k + 1]) << 16);
        *(uint4*)(Hbf + base) = make_uint4(o[0], o[1], o[2], o[3]);
    }
}

// ---------------- host
static inline size_t al256(size_t x) { return (x + 255) & ~(size_t)255; }

extern "C" void kernel_launch(void* const* d_in, const int* in_sizes, int n_in,
                              void* d_out, int out_size, void* d_ws, size_t ws_size,
                              hipStream_t stream) {
    const float* x    = (const float*)d_in[0];
    const int*   ei   = (const int*)d_in[1];
    const float* ew   = (const float*)d_in[2];
    const float* W_in = (const float*)d_in[3];
    const float* b_in = (const float*)d_in[4];
    const float* Ws[3] = {(const float*)d_in[5],  (const float*)d_in[11], (const float*)d_in[17]};
    const float* bs[3] = {(const float*)d_in[6],  (const float*)d_in[12], (const float*)d_in[18]};
    const float* Wn[3] = {(const float*)d_in[7],  (const float*)d_in[13], (const float*)d_in[19]};
    const float* bn[3] = {(const float*)d_in[8],  (const float*)d_in[14], (const float*)d_in[20]};
    const float* g[3]  = {(const float*)d_in[9],  (const float*)d_in[15], (const float*)d_in[21]};
    const float* be[3] = {(const float*)d_in[10], (const float*)d_in[16], (const float*)d_in[22]};

    char* ws = (char*)d_ws;
    size_t off = 0;
    const size_t nElem = (size_t)N_NODESC * DIM;          // 12.8M
    unsigned short* hbf    = (unsigned short*)(ws + off); off = al256(off + nElem * 2);
    unsigned short* xnbf   = (unsigned short*)(ws + off); off = al256(off + nElem * 2);
    unsigned short* tbuf   = (unsigned short*)(ws + off); off = al256(off + nElem * 2);
    unsigned short* wt     = (unsigned short*)(ws + off); off = al256(off + 7 * 16384 * 2);
    int*            counts = (int*)(ws + off);            off = al256(off + (size_t)N_NODESC * 4);
    int*            offs   = (int*)(ws + off);            off = al256(off + ((size_t)N_NODESC + 1) * 4);
    int*            rank   = (int*)(ws + off);            off = al256(off + (size_t)N_EDGESC * 4);
    int2*           edges  = (int2*)(ws + off);           off = al256(off + (size_t)N_EDGESC * 8);
    int*            bsum_  = (int*)(ws + off);            off = al256(off + SCAN_NB * 4);
    float*          stats  = (float*)(ws + off);          off = al256(off + 3 * 256 * 4);

    (void)hipMemsetAsync(counts, 0, (size_t)N_NODESC * 4, stream);
    (void)hipMemsetAsync(stats, 0, 3 * 256 * 4, stream);

    k_wcvt<<<448, 256, 0, stream>>>(W_in, Ws[0], Wn[0], Ws[1], Wn[1], Ws[2], Wn[2], wt);
    k_hist<<<HB, 256, 0, stream>>>(ei, counts, rank);
    k_scan_bsum<<<SCAN_NB, 256, 0, stream>>>(counts, bsum_);
    k_scan_write<<<SCAN_NB, 256, 0, stream>>>(counts, bsum_, offs);
    k_scatter<<<HB, 256, 0, stream>>>(ei, ew, offs, rank, edges);

    k_gemm_in<<<GB, 256, 0, stream>>>(x, wt, b_in, hbf, N_NODESC);

    for (int l = 0; l < 3; ++l) {
        k_agg<<<12500, 256, 0, stream>>>(hbf, offs, edges, xnbf);
        k_gemm_layer<<<GB, 256, 0, stream>>>(hbf, xnbf,
                                             wt + (size_t)(1 + 2 * l) * 16384,
                                             wt + (size_t)(2 + 2 * l) * 16384,
                                             bs[l], bn[l], tbuf,
                                             stats + l * 256, stats + l * 256 + 128, N_NODESC);
        if (l < 2)
            k_bn<1, 0><<<HB, 256, 0, stream>>>(tbuf, stats + l * 256, stats + l * 256 + 128,
                                               g[l], be[l], hbf, nullptr);
        else
            k_bn<0, 1><<<HB, 256, 0, stream>>>(tbuf, stats + l * 256, stats + l * 256 + 128,
                                               g[l], be[l], hbf, (float*)d_out);
    }
}

// Round 10
// 608.166 us; speedup vs baseline: 1.2987x; 1.0598x over previous
//
#include <hip/hip_runtime.h>

#define N_NODESC 100000
#define N_EDGESC 1600000
#define DIM 128
#define SCAN_NB 49    // ceil(100000 / 2048)
#define GB 782        // ceil(100000 / 128) gemm blocks
#define HB 6250       // hist / scatter blocks
#define TPAD 136      // LDS tile row stride in shorts

typedef __bf16 bf16x8 __attribute__((ext_vector_type(8)));
typedef unsigned short u16x8 __attribute__((ext_vector_type(8)));
typedef float f32x4 __attribute__((ext_vector_type(4)));

__device__ __forceinline__ float asf(unsigned u) { return __uint_as_float(u); }
__device__ __forceinline__ unsigned short f2bf(float f) {
    unsigned u = __float_as_uint(f);
    u += 0x7fffu + ((u >> 16) & 1u);
    return (unsigned short)(u >> 16);
}
__device__ __forceinline__ bf16x8 pack8(const float* f) {
    u16x8 u;
    #pragma unroll
    for (int i = 0; i < 8; ++i) u[i] = f2bf(f[i]);
    return __builtin_bit_cast(bf16x8, u);
}

// ---------------- weight convert: 7 matrices fp32 [k][c] -> bf16 FRAGMENT-MAJOR:
// linear index = ((kt*8 + nt)*64 + lane)*8 + j  maps to  W[(kt*32 + quad*8 + j)*128 + nt*16 + l15]
__global__ __launch_bounds__(256) void k_wcvt(const float* __restrict__ w0, const float* __restrict__ w1,
                                              const float* __restrict__ w2, const float* __restrict__ w3,
                                              const float* __restrict__ w4, const float* __restrict__ w5,
                                              const float* __restrict__ w6, unsigned short* __restrict__ wt) {
    int gid = blockIdx.x * 256 + threadIdx.x;   // 0..114687
    int m = gid >> 14;
    int r = gid & 16383;
    int j = r & 7;
    int lane = (r >> 3) & 63;
    int nt = (r >> 9) & 7;
    int kt = (r >> 12) & 3;
    int quad = lane >> 4;
    int l15 = lane & 15;
    const float* src;
    switch (m) {
        case 0: src = w0; break; case 1: src = w1; break; case 2: src = w2; break;
        case 3: src = w3; break; case 4: src = w4; break; case 5: src = w5; break;
        default: src = w6; break;
    }
    wt[gid] = f2bf(src[(kt * 32 + quad * 8 + j) * 128 + nt * 16 + l15]);
}

// ---------------- CSR pass A: histogram + per-edge rank (low VGPR, max occupancy)
__global__ __launch_bounds__(256) void k_hist(const int* __restrict__ ei, int* __restrict__ counts,
                                              int* __restrict__ rank) {
    int e = blockIdx.x * 256 + threadIdx.x;
    if (e < N_EDGESC) rank[e] = atomicAdd(&counts[ei[N_EDGESC + e]], 1);
}

// ---------------- CSR scan phase 1: per-block (2048 counts) sums
__global__ __launch_bounds__(256) void k_scan_bsum(const int* __restrict__ counts, int* __restrict__ bsum) {
    __shared__ int wsh[4];
    int b = blockIdx.x, t = threadIdx.x;
    int i0 = b * 2048 + t * 8;
    int s = 0;
    #pragma unroll
    for (int k = 0; k < 8; ++k) { int i = i0 + k; s += (i < N_NODESC) ? counts[i] : 0; }
    #pragma unroll
    for (int d = 1; d < 64; d <<= 1) s += __shfl_xor(s, d, 64);
    if ((t & 63) == 0) wsh[t >> 6] = s;
    __syncthreads();
    if (t == 0) bsum[b] = wsh[0] + wsh[1] + wsh[2] + wsh[3];
}

// ---------------- CSR scan phase 2: write exclusive prefixes
__global__ __launch_bounds__(256) void k_scan_write(const int* __restrict__ counts, const int* __restrict__ bsum,
                                                    int* __restrict__ offs) {
    __shared__ int woff[4];
    __shared__ int bbase_sh;
    int b = blockIdx.x, t = threadIdx.x;
    int lane = t & 63, wid = t >> 6;
    if (t < 64) {
        int vp = (t < b) ? bsum[t] : 0;
        int va = (t < SCAN_NB) ? bsum[t] : 0;
        #pragma unroll
        for (int d = 1; d < 64; d <<= 1) { vp += __shfl_xor(vp, d, 64); va += __shfl_xor(va, d, 64); }
        if (t == 0) {
            bbase_sh = vp;
            if (b == SCAN_NB - 1) offs[N_NODESC] = va;
        }
    }
    __syncthreads();
    int i0 = b * 2048 + t * 8;
    int c[8];
    int tsum = 0;
    #pragma unroll
    for (int k = 0; k < 8; ++k) { int i = i0 + k; c[k] = (i < N_NODESC) ? counts[i] : 0; tsum += c[k]; }
    int incl = tsum;
    #pragma unroll
    for (int d = 1; d < 64; d <<= 1) { int tt = __shfl_up(incl, d, 64); if (lane >= d) incl += tt; }
    if (lane == 63) woff[wid] = incl;
    __syncthreads();
    if (t == 0) {
        int s = 0;
        for (int k = 0; k < 4; ++k) { int tt = woff[k]; woff[k] = s; s += tt; }
    }
    __syncthreads();
    int base = bbase_sh + woff[wid] + (incl - tsum);
    #pragma unroll
    for (int k = 0; k < 8; ++k) {
        int i = i0 + k;
        if (i < N_NODESC) offs[i] = base;
        base += c[k];
    }
}

// ---------------- atomic-free scatter of combined 8B edge records
__global__ __launch_bounds__(256) void k_scatter(const int* __restrict__ ei, const float* __restrict__ ew,
                                                 const int* __restrict__ offs, const int* __restrict__ rank,
                                                 int2* __restrict__ edges) {
    int e = blockIdx.x * 256 + threadIdx.x;
    if (e >= N_EDGESC) return;
    int dst = ei[N_EDGESC + e];
    int p = offs[dst] + rank[e];
    edges[p] = make_int2(ei[e], __float_as_int(ew[e]));
}

// ---------------- aggregation: HALF-WAVE per node (2 nodes/wave)
__global__ __launch_bounds__(256) void k_agg(const unsigned short* __restrict__ hbf, const int* __restrict__ offs,
                                             const int2* __restrict__ edges, unsigned short* __restrict__ xnbf) {
    int tid = threadIdx.x;
    int q = tid & 15;
    int sub = (tid >> 4) & 1;
    int n = blockIdx.x * 8 + (tid >> 5);
    int s = offs[n], e = offs[n + 1];
    float acc[8] = {};
    float wsum = 0.f;
    for (int j = s; j < e; j += 8) {
        int idx[4];
        bool pr[4];
        int2 rec[4];
        #pragma unroll
        for (int u = 0; u < 4; ++u) {
            idx[u] = j + u * 2 + sub;
            pr[u] = idx[u] < e;
            rec[u] = edges[pr[u] ? idx[u] : s];
        }
        uint4 v[4];
        float w[4];
        #pragma unroll
        for (int u = 0; u < 4; ++u) {
            w[u] = pr[u] ? __int_as_float(rec[u].y) : 0.f;
            v[u] = *(const uint4*)(hbf + (size_t)rec[u].x * 128 + q * 8);
        }
        #pragma unroll
        for (int u = 0; u < 4; ++u) {
            unsigned uu[4] = {v[u].x, v[u].y, v[u].z, v[u].w};
            #pragma unroll
            for (int k = 0; k < 4; ++k) {
                acc[2 * k]     += w[u] * asf(uu[k] << 16);
                acc[2 * k + 1] += w[u] * asf(uu[k] & 0xffff0000u);
            }
            wsum += w[u];
        }
    }
    #pragma unroll
    for (int k = 0; k < 8; ++k) acc[k] += __shfl_xor(acc[k], 16, 64);
    wsum += __shfl_xor(wsum, 16, 64);
    float inv = 1.f / fmaxf(wsum, 1.f);
    if (((tid >> 4) & 1) == 0) {
        unsigned o[4];
        #pragma unroll
        for (int k = 0; k < 4; ++k)
            o[k] = (unsigned)f2bf(acc[2 * k] * inv) | ((unsigned)f2bf(acc[2 * k + 1] * inv) << 16);
        *(uint4*)(xnbf + (size_t)n * 128 + q * 8) = make_uint4(o[0], o[1], o[2], o[3]);
    }
}

// ---------------- input GEMM: hbf = bf16(relu(x @ W_in + b)); W staged in LDS once/block,
// tile aliases the weight LDS after MFMA (saves LDS -> 3 blocks/CU).
__global__ __launch_bounds__(256, 3) void k_gemm_in(const float* __restrict__ X,
                                                    const unsigned short* __restrict__ WF,
                                                    const float* __restrict__ bias,
                                                    unsigned short* __restrict__ Hbf, int M) {
    __shared__ unsigned short smem[128 * TPAD];   // >= 16384 (weights) and 128*TPAD (tile)
    int tid = threadIdx.x;
    int lane = tid & 63;
    int wid = tid >> 6;
    int l15 = lane & 15;
    int quad = lane >> 4;
    // stage W_in (16384 shorts) coalesced
    #pragma unroll
    for (int it = 0; it < 8; ++it) {
        int idx = (it * 256 + tid) * 8;
        *(uint4*)(smem + idx) = *(const uint4*)(WF + idx);
    }
    int rowbase = blockIdx.x * 128 + wid * 32;
    bf16x8 a[2][4];
    #pragma unroll
    for (int rs = 0; rs < 2; ++rs) {
        int ra = min(rowbase + rs * 16 + l15, M - 1);
        float buf[4][8];
        #pragma unroll
        for (int kt = 0; kt < 4; ++kt) {
            int k0 = kt * 32 + quad * 8;
            *(float4*)(buf[kt])     = *(const float4*)(X + (size_t)ra * 128 + k0);
            *(float4*)(buf[kt] + 4) = *(const float4*)(X + (size_t)ra * 128 + k0 + 4);
        }
        #pragma unroll
        for (int kt = 0; kt < 4; ++kt) a[rs][kt] = pack8(buf[kt]);
    }
    __syncthreads();
    f32x4 acc[2][8] = {};
    #pragma unroll
    for (int kt = 0; kt < 4; ++kt) {
        #pragma unroll
        for (int nt = 0; nt < 8; ++nt) {
            bf16x8 b = *(const bf16x8*)(smem + ((kt * 8 + nt) * 64 + lane) * 8);
            #pragma unroll
            for (int rs = 0; rs < 2; ++rs)
                acc[rs][nt] = __builtin_amdgcn_mfma_f32_16x16x32_bf16(a[rs][kt], b, acc[rs][nt], 0, 0, 0);
        }
    }
    __syncthreads();   // weights dead; reuse smem as output tile
    #pragma unroll
    for (int nt = 0; nt < 8; ++nt) {
        int c = nt * 16 + l15;
        float bv = bias[c];
        #pragma unroll
        for (int rs = 0; rs < 2; ++rs) {
            #pragma unroll
            for (int i = 0; i < 4; ++i) {
                int rl = wid * 32 + rs * 16 + quad * 4 + i;
                float v = fmaxf(acc[rs][nt][i] + bv, 0.f);
                smem[rl * TPAD + c] = f2bf(v);
            }
        }
    }
    __syncthreads();
    int rl = tid >> 1;
    int cs = (tid & 1) * 64;
    int gr = blockIdx.x * 128 + rl;
    if (gr < M) {
        #pragma unroll
        for (int k = 0; k < 8; ++k) {
            uint4 v = *(const uint4*)(smem + rl * TPAD + cs + k * 8);
            *(uint4*)(Hbf + (size_t)gr * 128 + cs + k * 8) = v;
        }
    }
}

// ---------------- layer GEMM: t_bf16 = h@Ws + xn@Wn + (bs+bn), + column stats.
// Both weight matrices (64 KB) staged in LDS once per block; tile aliases them after.
__global__ __launch_bounds__(256, 2) void k_gemm_layer(const unsigned short* __restrict__ Abf,
                                                       const unsigned short* __restrict__ Xbf,
                                                       const unsigned short* __restrict__ WsF,
                                                       const unsigned short* __restrict__ WnF,
                                                       const float* __restrict__ bs, const float* __restrict__ bn,
                                                       unsigned short* __restrict__ Tb,
                                                       float* __restrict__ colsum, float* __restrict__ colsq,
                                                       int M) {
    __shared__ unsigned short smem[32768];        // Ws[0..16384) + Wn[16384..32768); tile aliases [0..17408)
    __shared__ float s_sum[128];
    __shared__ float s_sq[128];
    int tid = threadIdx.x;
    if (tid < 128) { s_sum[tid] = 0.f; s_sq[tid] = 0.f; }
    // stage weights coalesced (16B/thread/iter)
    #pragma unroll
    for (int it = 0; it < 8; ++it) {
        int idx = (it * 256 + tid) * 8;
        *(uint4*)(smem + idx)         = *(const uint4*)(WsF + idx);
        *(uint4*)(smem + 16384 + idx) = *(const uint4*)(WnF + idx);
    }
    int lane = tid & 63;
    int wid = tid >> 6;
    int l15 = lane & 15;
    int quad = lane >> 4;
    int rowbase = blockIdx.x * 128 + wid * 32;
    bf16x8 ah[2][4], ax[2][4];
    #pragma unroll
    for (int rs = 0; rs < 2; ++rs) {
        int ra = min(rowbase + rs * 16 + l15, M - 1);
        #pragma unroll
        for (int kt = 0; kt < 4; ++kt) {
            int k0 = kt * 32 + quad * 8;
            ah[rs][kt] = *(const bf16x8*)(Abf + (size_t)ra * 128 + k0);
            ax[rs][kt] = *(const bf16x8*)(Xbf + (size_t)ra * 128 + k0);
        }
    }
    __syncthreads();
    f32x4 acc[2][8] = {};
    #pragma unroll
    for (int kt = 0; kt < 4; ++kt) {
        #pragma unroll
        for (int nt = 0; nt < 8; ++nt) {
            int fo = ((kt * 8 + nt) * 64 + lane) * 8;
            bf16x8 bsv = *(const bf16x8*)(smem + fo);
            bf16x8 bnv = *(const bf16x8*)(smem + 16384 + fo);
            #pragma unroll
            for (int rs = 0; rs < 2; ++rs) {
                acc[rs][nt] = __builtin_amdgcn_mfma_f32_16x16x32_bf16(ah[rs][kt], bsv, acc[rs][nt], 0, 0, 0);
                acc[rs][nt] = __builtin_amdgcn_mfma_f32_16x16x32_bf16(ax[rs][kt], bnv, acc[rs][nt], 0, 0, 0);
            }
        }
    }
    __syncthreads();   // weights dead; reuse smem as output tile
    #pragma unroll
    for (int nt = 0; nt < 8; ++nt) {
        int c = nt * 16 + l15;
        float bv = bs[c] + bn[c];
        float ps = 0.f, pq = 0.f;
        #pragma unroll
        for (int rs = 0; rs < 2; ++rs) {
            #pragma unroll
            for (int i = 0; i < 4; ++i) {
                int rl = wid * 32 + rs * 16 + quad * 4 + i;   // local row 0..127
                int r = blockIdx.x * 128 + rl;
                float v = acc[rs][nt][i] + bv;
                if (r < M) {
                    unsigned short qv = f2bf(v);
                    smem[rl * TPAD + c] = qv;
                    float vq = asf((unsigned)qv << 16);
                    ps += vq; pq += vq * vq;
                }
            }
        }
        ps += __shfl_xor(ps, 16); pq += __shfl_xor(pq, 16);
        ps += __shfl_xor(ps, 32); pq += __shfl_xor(pq, 32);
        if (quad == 0) { atomicAdd(&s_sum[c], ps); atomicAdd(&s_sq[c], pq); }
    }
    __syncthreads();
    int rl = tid >> 1;
    int cs = (tid & 1) * 64;
    int gr = blockIdx.x * 128 + rl;
    if (gr < M) {
        #pragma unroll
        for (int k = 0; k < 8; ++k) {
            uint4 v = *(const uint4*)(smem + rl * TPAD + cs + k * 8);
            *(uint4*)(Tb + (size_t)gr * 128 + cs + k * 8) = v;
        }
    }
    if (tid < 128) atomicAdd(&colsum[tid], s_sum[tid]);
    else atomicAdd(&colsq[tid - 128], s_sq[tid - 128]);
}

// ---------------- BN apply + residual; residual chain lives in bf16 (Hbf)
template <int RELU, int FINAL>
__global__ __launch_bounds__(256) void k_bn(const unsigned short* __restrict__ Tb,
                                            const float* __restrict__ colsum,
                                            const float* __restrict__ colsq, const float* __restrict__ gma,
                                            const float* __restrict__ bta,
                                            unsigned short* __restrict__ Hbf, float* __restrict__ Out) {
    size_t base = ((size_t)blockIdx.x * 256 + threadIdx.x) * 8;
    int c0 = (int)(base & 127);
    uint4 tv = *(const uint4*)(Tb + base);
    unsigned w[4] = {tv.x, tv.y, tv.z, tv.w};
    float tt[8];
    #pragma unroll
    for (int k = 0; k < 4; ++k) {
        tt[2 * k]     = asf(w[k] << 16);
        tt[2 * k + 1] = asf(w[k] & 0xffff0000u);
    }
    uint4 hv = *(const uint4*)(Hbf + base);
    unsigned hw[4] = {hv.x, hv.y, hv.z, hv.w};
    float hh[8];
    #pragma unroll
    for (int k = 0; k < 4; ++k) {
        hh[2 * k]     = asf(hw[k] << 16);
        hh[2 * k + 1] = asf(hw[k] & 0xffff0000u);
    }
    float ss[8], qq[8], gg[8], bb[8];
    *(float4*)ss       = *(const float4*)(colsum + c0);
    *(float4*)(ss + 4) = *(const float4*)(colsum + c0 + 4);
    *(float4*)qq       = *(const float4*)(colsq + c0);
    *(float4*)(qq + 4) = *(const float4*)(colsq + c0 + 4);
    *(float4*)gg       = *(const float4*)(gma + c0);
    *(float4*)(gg + 4) = *(const float4*)(gma + c0 + 4);
    *(float4*)bb       = *(const float4*)(bta + c0);
    *(float4*)(bb + 4) = *(const float4*)(bta + c0 + 4);
    const float invM = 1.0f / (float)N_NODESC;
    float r[8];
    #pragma unroll
    for (int j = 0; j < 8; ++j) {
        float mu = ss[j] * invM;
        float var = qq[j] * invM - mu * mu;
        float is = rsqrtf(var + 1e-5f);
        float v = (tt[j] - mu) * is * gg[j] + bb[j];
        if (RELU) v = fmaxf(v, 0.f);
        r[j] = hh[j] + v;
    }
    if (FINAL) {
        *(float4*)(Out + base)     = make_float4(r[0], r[1], r[2], r[3]);
        *(float4*)(Out + base + 4) = make_float4(r[4], r[5], r[6], r[7]);
    } else {
        unsigned o[4];
        #pragma unroll
        for (int k = 0; k < 4; ++k)
            o[k] = (unsigned)f2bf(r[2 * k]) | ((unsigned)f2bf(r[2 * k + 1]) << 16);
        *(uint4*)(Hbf + base) = make_uint4(o[0], o[1], o[2], o[3]);
    }
}

// ---------------- host
static inline size_t al256(size_t x) { return (x + 255) & ~(size_t)255; }

extern "C" void kernel_launch(void* const* d_in, const int* in_sizes, int n_in,
                              void* d_out, int out_size, void* d_ws, size_t ws_size,
                              hipStream_t stream) {
    const float* x    = (const float*)d_in[0];
    const int*   ei   = (const int*)d_in[1];
    const float* ew   = (const float*)d_in[2];
    const float* W_in = (const float*)d_in[3];
    const float* b_in = (const float*)d_in[4];
    const float* Ws[3] = {(const float*)d_in[5],  (const float*)d_in[11], (const float*)d_in[17]};
    const float* bs[3] = {(const float*)d_in[6],  (const float*)d_in[12], (const float*)d_in[18]};
    const float* Wn[3] = {(const float*)d_in[7],  (const float*)d_in[13], (const float*)d_in[19]};
    const float* bn[3] = {(const float*)d_in[8],  (const float*)d_in[14], (const float*)d_in[20]};
    const float* g[3]  = {(const float*)d_in[9],  (const float*)d_in[15], (const float*)d_in[21]};
    const float* be[3] = {(const float*)d_in[10], (const float*)d_in[16], (const float*)d_in[22]};

    char* ws = (char*)d_ws;
    size_t off = 0;
    const size_t nElem = (size_t)N_NODESC * DIM;          // 12.8M
    unsigned short* hbf    = (unsigned short*)(ws + off); off = al256(off + nElem * 2);
    unsigned short* xnbf   = (unsigned short*)(ws + off); off = al256(off + nElem * 2);
    unsigned short* tbuf   = (unsigned short*)(ws + off); off = al256(off + nElem * 2);
    unsigned short* wt     = (unsigned short*)(ws + off); off = al256(off + 7 * 16384 * 2);
    int*            counts = (int*)(ws + off);            off = al256(off + (size_t)N_NODESC * 4);
    int*            offs   = (int*)(ws + off);            off = al256(off + ((size_t)N_NODESC + 1) * 4);
    int*            rank   = (int*)(ws + off);            off = al256(off + (size_t)N_EDGESC * 4);
    int2*           edges  = (int2*)(ws + off);           off = al256(off + (size_t)N_EDGESC * 8);
    int*            bsum_  = (int*)(ws + off);            off = al256(off + SCAN_NB * 4);
    float*          stats  = (float*)(ws + off);          off = al256(off + 3 * 256 * 4);

    (void)hipMemsetAsync(counts, 0, (size_t)N_NODESC * 4, stream);
    (void)hipMemsetAsync(stats, 0, 3 * 256 * 4, stream);

    k_wcvt<<<448, 256, 0, stream>>>(W_in, Ws[0], Wn[0], Ws[1], Wn[1], Ws[2], Wn[2], wt);
    k_hist<<<HB, 256, 0, stream>>>(ei, counts, rank);
    k_scan_bsum<<<SCAN_NB, 256, 0, stream>>>(counts, bsum_);
    k_scan_write<<<SCAN_NB, 256, 0, stream>>>(counts, bsum_, offs);
    k_scatter<<<HB, 256, 0, stream>>>(ei, ew, offs, rank, edges);

    k_gemm_in<<<GB, 256, 0, stream>>>(x, wt, b_in, hbf, N_NODESC);

    for (int l = 0; l < 3; ++l) {
        k_agg<<<12500, 256, 0, stream>>>(hbf, offs, edges, xnbf);
        k_gemm_layer<<<GB, 256, 0, stream>>>(hbf, xnbf,
                                             wt + (size_t)(1 + 2 * l) * 16384,
                                             wt + (size_t)(2 + 2 * l) * 16384,
                                             bs[l], bn[l], tbuf,
                                             stats + l * 256, stats + l * 256 + 128, N_NODESC);
        if (l < 2)
            k_bn<1, 0><<<HB, 256, 0, stream>>>(tbuf, stats + l * 256, stats + l * 256 + 128,
                                               g[l], be[l], hbf, nullptr);
        else
            k_bn<0, 1><<<HB, 256, 0, stream>>>(tbuf, stats + l * 256, stats + l * 256 + 128,
                                               g[l], be[l], hbf, (float*)d_out);
    }
}